// Round 4
// baseline (408.931 us; speedup 1.0000x reference)
//
#include <hip/hip_runtime.h>

// Local NCC loss on (2,1,160,160,160) f32, 5x5x5 box window, SAME zero pad.
// Block = 320 thr (5 waves), tile = 160W x 8H x 8D, grid = 800 blocks.
// Full-width rows staged in LDS (dbuf, +2-shifted with zero pads for W edges);
// each thread owns one f4 W-strip: 20 ds_read_b128/slab -> vertical 5-sums of
// {I,J,I2,J2,IJ} -> sliding W 5-window -> 5 compile-time D-phase f4 accumulators.
// 12-slab loop fully unrolled: all phase indexing static (no scratch).

#define DIM 160
#define SLAB (DIM * DIM)          // 25600
#define VOL (DIM * DIM * DIM)     // 4096000
#define TD 8
#define ROWS 12                   // TD/H halo rows staged: 8+4
#define RST 168                   // padded row stride (floats): [2..161]=w 0..159
#define NBLK 800
#define NPART (NBLK * 5)

typedef float f4 __attribute__((ext_vector_type(4), aligned(16)));
typedef float f2 __attribute__((ext_vector_type(2), aligned(8)));

__device__ __forceinline__ f4 hwin(const f4 lo, const f4 hi) {
    // 5-wide sliding sums over the 8 values [lo.xyzw, hi.xyzw]
    const float c0 = ((lo.x + lo.y) + (lo.z + lo.w)) + hi.x;
    const float c1 = c0 - lo.x + hi.y;
    const float c2 = c1 - lo.y + hi.z;
    const float c3 = c2 - lo.z + hi.w;
    return (f4){c0, c1, c2, c3};
}

__global__ __launch_bounds__(320, 3) void ncc_main(const float* __restrict__ real,
                                                   const float* __restrict__ fake,
                                                   float* __restrict__ partials) {
    __shared__ float lds[2][2][ROWS][RST];   // [buf][vol][row][x]  32256 B

    const int tid = threadIdx.x;

    // XCD-chunked swizzle: 800 blocks -> 8 chunks of 100 (D-neighbors same XCD)
    const int bid = blockIdx.x;
    const int vid = (bid & 7) * 100 + (bid >> 3);
    const int by  = vid / 40;              // 0..19
    const int r2  = vid - 40 * by;
    const int nb  = r2 / 20;               // batch
    const int dz  = r2 - 20 * nb;          // 0..19
    const int h0 = by * 8, d0 = dz * 8;

    const float* baseI = real + (size_t)nb * VOL;
    const float* baseJ = fake + (size_t)nb * VOL;

    // compute mapping: one f4 output strip at (row r, w=4c..4c+3)
    const int r  = tid / 40;               // 0..7
    const int c  = tid - 40 * r;           // 0..39
    const int co = r * RST + 4 * c;

    // staging tasks: 960 = 2 vols x 12 rows x 40 quads; exactly 3 per thread
    int goff[3], loff[3];
    float okf[3];
    const float* tp[3];
#pragma unroll
    for (int k = 0; k < 3; ++k) {
        const int idx = tid + 320 * k;
        const int v   = idx / 480;
        const int rem = idx - 480 * v;
        const int row = rem / 40;
        const int q   = rem - 40 * row;
        const int h   = h0 - 2 + row;
        okf[k] = ((unsigned)h < DIM) ? 1.f : 0.f;
        const int hc = min(max(h, 0), DIM - 1);
        goff[k] = hc * DIM + 4 * q;
        loff[k] = (v * ROWS + row) * RST + 2 + 4 * q;
        tp[k]   = v ? baseJ : baseI;
    }

    // zero all LDS once (covers W pads + D-edge prologue)
    {
        float* L = &lds[0][0][0][0];
        for (int i = tid; i < 2 * 2 * ROWS * RST; i += 320) L[i] = 0.f;
    }
    __syncthreads();

    // prologue: stage slab dd=d0-2 into buf0 (skip if OOB; buffer already zero)
    {
        const int dd = d0 - 2;
        if (dd >= 0) {
            float* Sb = &lds[0][0][0][0];
#pragma unroll
            for (int k = 0; k < 3; ++k) {
                f4 v = *(const f4*)(tp[k] + (size_t)dd * SLAB + goff[k]);
                const float m = okf[k];
                v.x *= m; v.y *= m; v.z *= m; v.w *= m;
                *(f2*)(Sb + loff[k])     = (f2){v.x, v.y};
                *(f2*)(Sb + loff[k] + 2) = (f2){v.z, v.w};
            }
        }
    }
    __syncthreads();

    const f4 zf = (f4){0.f, 0.f, 0.f, 0.f};
    f4 zs[5][5];
#pragma unroll
    for (int p = 0; p < 5; ++p)
#pragma unroll
        for (int q = 0; q < 5; ++q) zs[p][q] = zf;

    f4 acc = zf;
    const float inv = 1.0f / 125.0f;

#pragma unroll
    for (int s = 0; s < 12; ++s) {
        const int cur = s & 1;

        // ---- issue next-slab global loads (3 aligned f4, reg-held) ----
        f4 p0 = zf, p1 = zf, p2 = zf;
        if (s < 11) {
            const int dd1 = d0 - 1 + s;
            if ((unsigned)dd1 < DIM) {
                const size_t so = (size_t)dd1 * SLAB;
                p0 = *(const f4*)(tp[0] + so + goff[0]);
                p1 = *(const f4*)(tp[1] + so + goff[1]);
                p2 = *(const f4*)(tp[2] + so + goff[2]);
                p0.x *= okf[0]; p0.y *= okf[0]; p0.z *= okf[0]; p0.w *= okf[0];
                p1.x *= okf[1]; p1.y *= okf[1]; p1.z *= okf[1]; p1.w *= okf[1];
                p2.x *= okf[2]; p2.y *= okf[2]; p2.z *= okf[2]; p2.w *= okf[2];
            }
        }

        // ---- compute this slab: vertical 5-sums from 20 b128 reads ----
        const float* LI = &lds[cur][0][0][0];
        const float* LJ = LI + ROWS * RST;
        f4 vI0 = zf, vI1 = zf, vJ0 = zf, vJ1 = zf;
        f4 vI20 = zf, vI21 = zf, vJ20 = zf, vJ21 = zf, vIJ0 = zf, vIJ1 = zf;
#pragma unroll
        for (int t = 0; t < 5; ++t) {
            const int o = co + t * RST;
            const f4 a0 = *(const f4*)(LI + o);
            const f4 a1 = *(const f4*)(LI + o + 4);
            const f4 b0 = *(const f4*)(LJ + o);
            const f4 b1 = *(const f4*)(LJ + o + 4);
            vI0 += a0; vI1 += a1; vJ0 += b0; vJ1 += b1;
            vI20 += a0 * a0; vI21 += a1 * a1;
            vJ20 += b0 * b0; vJ21 += b1 * b1;
            vIJ0 += a0 * b0; vIJ1 += a1 * b1;
        }
        f4 cs0 = hwin(vI0, vI1);
        f4 cs1 = hwin(vJ0, vJ1);
        f4 cs2 = hwin(vI20, vI21);
        f4 cs3 = hwin(vJ20, vJ21);
        f4 cs4 = hwin(vIJ0, vIJ1);

        // ---- add to active D-phases (all conditions compile-time) ----
#pragma unroll
        for (int p = 0; p < 5; ++p) {
            const int start = s - ((s - p + 10) % 5);
            if (start >= 0 && start <= TD - 1) {
                zs[p][0] += cs0; zs[p][1] += cs1; zs[p][2] += cs2;
                zs[p][3] += cs3; zs[p][4] += cs4;
            }
        }

        // ---- completed phase -> cc for 4 outputs at depth d0+s-4 ----
        if (s >= 4) {
            const int pe = (s - 4) % 5;   // compile-time
            const f4 SI = zs[pe][0], SJ = zs[pe][1];
            const f4 S2I = zs[pe][2], S2J = zs[pe][3], SIJ = zs[pe][4];
            const f4 t0    = SI * inv;
            const f4 cross = SIJ - t0 * SJ;
            const f4 iv    = S2I - t0 * SI;
            const f4 jv    = S2J - (SJ * inv) * SJ;
            acc += cross * cross / (iv * jv + 1e-5f);
            zs[pe][0] = zf; zs[pe][1] = zf; zs[pe][2] = zf;
            zs[pe][3] = zf; zs[pe][4] = zf;
        }

        // ---- write reg-held next slab into other buffer ----
        if (s < 11) {
            float* Sb = &lds[cur ^ 1][0][0][0];
            *(f2*)(Sb + loff[0])     = (f2){p0.x, p0.y};
            *(f2*)(Sb + loff[0] + 2) = (f2){p0.z, p0.w};
            *(f2*)(Sb + loff[1])     = (f2){p1.x, p1.y};
            *(f2*)(Sb + loff[1] + 2) = (f2){p1.z, p1.w};
            *(f2*)(Sb + loff[2])     = (f2){p2.x, p2.y};
            *(f2*)(Sb + loff[2] + 2) = (f2){p2.z, p2.w};
        }
        __syncthreads();
    }

    // ---- wave reduction -> one partial per wave ----
    float a = (acc.x + acc.y) + (acc.z + acc.w);
#pragma unroll
    for (int off = 32; off; off >>= 1)
        a += __shfl_down(a, off, 64);
    if ((tid & 63) == 0)
        partials[bid * 5 + (tid >> 6)] = a;
}

__global__ void ncc_reduce(const float* __restrict__ partials, float* __restrict__ out) {
    __shared__ double ws[4];
    double s = 0.0;
    for (int i = threadIdx.x; i < NPART; i += 256) s += (double)partials[i];
#pragma unroll
    for (int off = 32; off; off >>= 1)
        s += __shfl_down(s, off, 64);
    if ((threadIdx.x & 63) == 0) ws[threadIdx.x >> 6] = s;
    __syncthreads();
    if (threadIdx.x == 0) {
        const double t = ws[0] + ws[1] + ws[2] + ws[3];
        out[0] = (float)(t / (2.0 * (double)VOL));
    }
}

extern "C" void kernel_launch(void* const* d_in, const int* in_sizes, int n_in,
                              void* d_out, int out_size, void* d_ws, size_t ws_size,
                              hipStream_t stream) {
    const float* real = (const float*)d_in[0];
    const float* fake = (const float*)d_in[1];
    float* out      = (float*)d_out;
    float* partials = (float*)d_ws;   // NPART floats

    ncc_main<<<dim3(NBLK), dim3(320), 0, stream>>>(real, fake, partials);
    ncc_reduce<<<1, 256, 0, stream>>>(partials, out);
}

// Round 5
// 57.752 us; speedup vs baseline: 7.0808x; 7.0808x over previous
//
#include <hip/hip_runtime.h>

// Local NCC loss on (2,1,160,160,160) f32, 5x5x5 box window, SAME zero pad.
// Block 256 thr (4 waves), tile 32W x 32H x 16D, grid 500 blocks.
// Raw I/J staged in LDS (dbuf, +2-shifted, RST=44 padded); each thread owns a
// 4-wide W strip: 20 ds_read_b128/slab -> vertical 5-sums of {I,J,I2,J2,IJ}
// -> sliding W 5-window (hwin) -> 5 compile-time D-phase f4 accumulators in
// REGISTERS (launch_bounds(256,2) so they do NOT spill - R4's 413us was spill).

#define DIM 160
#define SLAB (DIM * DIM)
#define VOL (DIM * DIM * DIM)
#define TD 16
#define ROWS 36                   // staged H rows: 32 + 4 halo
#define RST 44                    // padded row stride (floats), 44%32=12 bank skew
#define NBLK 500
#define NPART (NBLK * 4)

typedef float f4 __attribute__((ext_vector_type(4), aligned(16)));
typedef float f2 __attribute__((ext_vector_type(2), aligned(8)));

__device__ __forceinline__ f4 hwin(const f4 lo, const f4 hi) {
    // sliding 5-sums: out j corresponds to window lo[j]..lo[3],hi[0]..  (w-2..w+2)
    const float c0 = ((lo.x + lo.y) + (lo.z + lo.w)) + hi.x;
    const float c1 = c0 - lo.x + hi.y;
    const float c2 = c1 - lo.y + hi.z;
    const float c3 = c2 - lo.z + hi.w;
    return (f4){c0, c1, c2, c3};
}

__global__ __launch_bounds__(256, 2) void ncc_main(const float* __restrict__ real,
                                                   const float* __restrict__ fake,
                                                   float* __restrict__ partials) {
    __shared__ __align__(16) float raw[2][2][ROWS][RST];   // [buf][vol][row][x] 25344 B

    const int tid = threadIdx.x;
    const int bx = blockIdx.x, by = blockIdx.y, bz = blockIdx.z;
    const int w0 = 32 * bx, h0 = 32 * by;
    const int nb = bz / 10;
    const int d0 = (bz - 10 * nb) * TD;

    const float* baseI = real + (size_t)nb * VOL;
    const float* baseJ = fake + (size_t)nb * VOL;

    // compute mapping: strip (sr=row 0..31, sc=0..7 -> w = w0+4sc..w0+4sc+3)
    const int sr = tid >> 3;
    const int sc = tid & 7;
    const int co = sr * RST + 4 * sc;      // f4 reads at co and co+4 (+t*RST)

    // staging: 720 tasks = 2 vols x 36 rows x 10 quads; 3 per thread (some idle)
    int gof[3], lof[3];
    bool ok[3], wlo[3];
    const float* src[3];
#pragma unroll
    for (int k = 0; k < 3; ++k) {
        const int t   = tid + 256 * k;
        const int tv  = t / 360;
        const int rem = t - 360 * tv;
        const int row = rem / 10;
        const int q   = rem - 10 * row;
        const int hg  = h0 - 2 + row;
        const int wq  = w0 - 4 + 4 * q;    // aligned quad start
        const bool okh = (unsigned)hg < DIM;
        const bool okw = (wq >= 0) && (wq + 3 < DIM);   // quads fully in or out
        ok[k]  = (t < 720) && okh && okw;
        wlo[k] = ok[k] && (q > 0);         // lo-f2 lands at idx 4q-2 (invalid q=0)
        gof[k] = hg * DIM + wq;
        lof[k] = (tv * ROWS + row) * RST + 4 * q - 2;
        src[k] = tv ? baseJ : baseI;
    }

    // zero LDS once (halo slots that staging never writes stay zero forever)
    {
        float* L = &raw[0][0][0][0];
        for (int i = tid; i < 2 * 2 * ROWS * RST; i += 256) L[i] = 0.f;
    }
    __syncthreads();

    // prologue: stage slab dd = d0-2 into buf0 (d0==0 -> OOB, buffer already zero)
    if (d0 > 0) {
        const size_t so = (size_t)(d0 - 2) * SLAB;
        float* L = &raw[0][0][0][0];
#pragma unroll
        for (int k = 0; k < 3; ++k) {
            if (ok[k]) {
                const f4 v = *(const f4*)(src[k] + so + gof[k]);
                if (wlo[k]) *(f2*)(L + lof[k]) = (f2){v.x, v.y};
                *(f2*)(L + lof[k] + 2) = (f2){v.z, v.w};
            }
        }
    }
    __syncthreads();

    const f4 zf = (f4){0.f, 0.f, 0.f, 0.f};
    f4 zs[5][5];                           // [phase][quantity], all static-indexed
#pragma unroll
    for (int p = 0; p < 5; ++p)
#pragma unroll
        for (int q = 0; q < 5; ++q) zs[p][q] = zf;

    f4 acc = zf;
    const float inv = 1.0f / 125.0f;
    int cur = 0;

    for (int a = 0; a < 4; ++a) {          // 4 x 5 = 20 slabs
        const bool am0 = (a > 0);
        const bool am3 = (a < 3);
#pragma unroll
        for (int b = 0; b < 5; ++b) {
            const int s   = 5 * a + b;
            const int dd1 = d0 - 1 + s;    // next slab to prefetch
            const bool pf = (b < 4) ? true : am3;   // s < 19

            // ---- issue next-slab loads into registers ----
            f4 v0 = zf, v1 = zf, v2 = zf;
            if (pf) {
                const bool dok = ((unsigned)dd1 < DIM);
                const size_t so = (size_t)dd1 * SLAB;
                if (dok) {
                    if (ok[0]) v0 = *(const f4*)(src[0] + so + gof[0]);
                    if (ok[1]) v1 = *(const f4*)(src[1] + so + gof[1]);
                    if (ok[2]) v2 = *(const f4*)(src[2] + so + gof[2]);
                }
            }

            // ---- compute current slab: vertical 5-sums from 20 b128 reads ----
            const float* LI = &raw[cur][0][0][0];
            const float* LJ = &raw[cur][1][0][0];
            f4 vI0 = zf, vI1 = zf, vJ0 = zf, vJ1 = zf;
            f4 vI20 = zf, vI21 = zf, vJ20 = zf, vJ21 = zf, vIJ0 = zf, vIJ1 = zf;
#pragma unroll
            for (int t = 0; t < 5; ++t) {
                const int o = co + t * RST;
                const f4 a0 = *(const f4*)(LI + o);
                const f4 a1 = *(const f4*)(LI + o + 4);
                const f4 b0 = *(const f4*)(LJ + o);
                const f4 b1 = *(const f4*)(LJ + o + 4);
                vI0 += a0; vI1 += a1; vJ0 += b0; vJ1 += b1;
                vI20 += a0 * a0; vI21 += a1 * a1;
                vJ20 += b0 * b0; vJ21 += b1 * b1;
                vIJ0 += a0 * b0; vIJ1 += a1 * b1;
            }
            const f4 cs0 = hwin(vI0, vI1);
            const f4 cs1 = hwin(vJ0, vJ1);
            const f4 cs2 = hwin(vI20, vI21);
            const f4 cs3 = hwin(vJ20, vJ21);
            const f4 cs4 = hwin(vIJ0, vIJ1);

            // ---- add into active phases (indices static; guards uniform bools) ----
#pragma unroll
            for (int p = 0; p < 5; ++p) {
                const int m = (b - p + 5) % 5;          // compile-time
                const bool doadd = (b >= m ? true : am0) && (b <= m ? true : am3);
                if (doadd) {
                    zs[p][0] += cs0; zs[p][1] += cs1; zs[p][2] += cs2;
                    zs[p][3] += cs3; zs[p][4] += cs4;
                }
            }

            // ---- completed phase (od = s-4) -> cc for 4 outputs ----
            if ((b == 4) ? true : am0) {
                const int pe = (b + 1) % 5;             // compile-time
                const f4 SI = zs[pe][0], SJ = zs[pe][1];
                const f4 S2I = zs[pe][2], S2J = zs[pe][3], SIJ = zs[pe][4];
                const f4 t0    = SI * inv;
                const f4 cross = SIJ - t0 * SJ;
                const f4 iv    = S2I - t0 * SI;
                const f4 jv    = S2J - (SJ * inv) * SJ;
                acc += cross * cross / (iv * jv + 1e-5f);
                zs[pe][0] = zf; zs[pe][1] = zf; zs[pe][2] = zf;
                zs[pe][3] = zf; zs[pe][4] = zf;
            }

            // ---- write prefetched regs into other buffer, flip ----
            if (pf) {
                float* L = &raw[cur ^ 1][0][0][0];
                if (wlo[0]) *(f2*)(L + lof[0]) = (f2){v0.x, v0.y};
                if (ok[0])  *(f2*)(L + lof[0] + 2) = (f2){v0.z, v0.w};
                if (wlo[1]) *(f2*)(L + lof[1]) = (f2){v1.x, v1.y};
                if (ok[1])  *(f2*)(L + lof[1] + 2) = (f2){v1.z, v1.w};
                if (wlo[2]) *(f2*)(L + lof[2]) = (f2){v2.x, v2.y};
                if (ok[2])  *(f2*)(L + lof[2] + 2) = (f2){v2.z, v2.w};
            }
            __syncthreads();
            cur ^= 1;
        }
    }

    // ---- wave reduction -> one partial per wave ----
    float a2 = (acc.x + acc.y) + (acc.z + acc.w);
#pragma unroll
    for (int off = 32; off; off >>= 1)
        a2 += __shfl_down(a2, off, 64);
    if ((tid & 63) == 0) {
        const int blin = (bz * gridDim.y + by) * gridDim.x + bx;
        partials[blin * 4 + (tid >> 6)] = a2;
    }
}

__global__ void ncc_reduce(const float* __restrict__ partials, float* __restrict__ out) {
    __shared__ double ws[4];
    double s = 0.0;
    for (int i = threadIdx.x; i < NPART; i += 256) s += (double)partials[i];
#pragma unroll
    for (int off = 32; off; off >>= 1)
        s += __shfl_down(s, off, 64);
    if ((threadIdx.x & 63) == 0) ws[threadIdx.x >> 6] = s;
    __syncthreads();
    if (threadIdx.x == 0) {
        const double t = ws[0] + ws[1] + ws[2] + ws[3];
        out[0] = (float)(t / (2.0 * (double)VOL));
    }
}

extern "C" void kernel_launch(void* const* d_in, const int* in_sizes, int n_in,
                              void* d_out, int out_size, void* d_ws, size_t ws_size,
                              hipStream_t stream) {
    const float* real = (const float*)d_in[0];
    const float* fake = (const float*)d_in[1];
    float* out      = (float*)d_out;
    float* partials = (float*)d_ws;   // NPART floats

    dim3 grid(5, 5, 20);
    ncc_main<<<grid, dim3(256), 0, stream>>>(real, fake, partials);
    ncc_reduce<<<1, 256, 0, stream>>>(partials, out);
}